// Round 1
// baseline (433.206 us; speedup 1.0000x reference)
//
#include <hip/hip_runtime.h>
#include <stdint.h>

// Problem constants (B=8, T=1024, D=512, H=8, dk=64)
#define Bc 8
#define Tc 1024
#define Dc 512
#define Hc 8
#define DKc 64

typedef __bf16 bf16x8 __attribute__((ext_vector_type(8)));
typedef float f32x4 __attribute__((ext_vector_type(4)));
typedef unsigned short ushort8v __attribute__((ext_vector_type(8)));

__device__ __forceinline__ unsigned short f2bf(float f) {
    union { float f; uint32_t u; } v; v.f = f;
    uint32_t u = v.u;
    u += 0x7fffu + ((u >> 16) & 1u);   // RNE
    return (unsigned short)(u >> 16);
}
__device__ __forceinline__ float bf2f(unsigned short s) {
    union { uint32_t u; float f; } v; v.u = ((uint32_t)s) << 16;
    return v.f;
}
__device__ __forceinline__ f32x4 mfma16(bf16x8 a, bf16x8 b, f32x4 c) {
    return __builtin_amdgcn_mfma_f32_16x16x32_bf16(a, b, c, 0, 0, 0);
}

// ---------------------------------------------------------------------------
// Generic GEMM: C[n,m] = sum_k A[n,k] * W[m,k]  (A: [N,512] f32 or bf16,
// W: [512,512] f32, converted to bf16 in staging). 128x128 tile, 4 waves.
// EPI: 0 = write q_u=C+bq+bias_u and q_v=C+bq+bias_v (bf16)
//      1 = write C+bias (bf16)
//      2 = write C+bias transposed to [b,h,d,t] (bf16)
//      3 = write C (bf16), no bias
//      4 = write C+bias as fp32 (final output)
// ---------------------------------------------------------------------------
template<int EPI, bool AF32>
__global__ __launch_bounds__(256) void gemm_nt(
    const void* __restrict__ Ap, const float* __restrict__ Wmat,
    const float* __restrict__ bias,
    const float* __restrict__ bias_u, const float* __restrict__ bias_v,
    unsigned short* __restrict__ out0, unsigned short* __restrict__ out1,
    float* __restrict__ fout)
{
    const int n0 = blockIdx.x * 128, m0 = blockIdx.y * 128;
    __shared__ unsigned short As[128][72];   // +8 pad (16B-aligned rows, 2-way banks)
    __shared__ unsigned short Bs[128][72];
    const int tid = threadIdx.x, lane = tid & 63, wave = tid >> 6;
    const int lrow = lane & 15, lkg = lane >> 4;
    const int wr = (wave >> 1) * 64, wc = (wave & 1) * 64;

    f32x4 acc[4][4];
#pragma unroll
    for (int i = 0; i < 4; ++i)
#pragma unroll
        for (int j = 0; j < 4; ++j) acc[i][j] = f32x4{0.f, 0.f, 0.f, 0.f};

    for (int kt = 0; kt < 512; kt += 64) {
        __syncthreads();
        // stage A (128x64) and W (128x64), convert to bf16
#pragma unroll
        for (int it = 0; it < 4; ++it) {
            int c = tid + it * 256;          // 1024 chunks of 8 elems
            int r = c >> 3, kc = (c & 7) * 8;
            if (AF32) {
                const float* src = (const float*)Ap + (size_t)(n0 + r) * 512 + kt + kc;
                ushort8v v;
#pragma unroll
                for (int j = 0; j < 8; ++j) v[j] = f2bf(src[j]);
                *(ushort8v*)&As[r][kc] = v;
            } else {
                const unsigned short* src = (const unsigned short*)Ap + (size_t)(n0 + r) * 512 + kt + kc;
                *(ushort8v*)&As[r][kc] = *(const ushort8v*)src;
            }
            const float* wsrc = Wmat + (size_t)(m0 + r) * 512 + kt + kc;
            ushort8v w;
#pragma unroll
            for (int j = 0; j < 8; ++j) w[j] = f2bf(wsrc[j]);
            *(ushort8v*)&Bs[r][kc] = w;
        }
        __syncthreads();
#pragma unroll
        for (int kk = 0; kk < 2; ++kk) {
            bf16x8 a[4], bb[4];
#pragma unroll
            for (int i = 0; i < 4; ++i)
                a[i] = *(const bf16x8*)&As[wr + i * 16 + lrow][kk * 32 + lkg * 8];
#pragma unroll
            for (int j = 0; j < 4; ++j)
                bb[j] = *(const bf16x8*)&Bs[wc + j * 16 + lrow][kk * 32 + lkg * 8];
#pragma unroll
            for (int i = 0; i < 4; ++i)
#pragma unroll
                for (int j = 0; j < 4; ++j)
                    acc[i][j] = mfma16(a[i], bb[j], acc[i][j]);
        }
    }

    // epilogue: C row = n0+wr+i*16+lkg*4+q, col = m0+wc+j*16+lrow
#pragma unroll
    for (int i = 0; i < 4; ++i) {
        int nbase = n0 + wr + i * 16 + lkg * 4;
#pragma unroll
        for (int j = 0; j < 4; ++j) {
            int m = m0 + wc + j * 16 + lrow;
            float bb = (EPI == 3) ? 0.f : bias[m];
            float bu = 0.f, bv = 0.f;
            if (EPI == 0) { bu = bias_u[m]; bv = bias_v[m]; }
#pragma unroll
            for (int q = 0; q < 4; ++q) {
                int n = nbase + q;
                float c = acc[i][j][q] + bb;
                if (EPI == 0) {
                    out0[(size_t)n * 512 + m] = f2bf(c + bu);
                    out1[(size_t)n * 512 + m] = f2bf(c + bv);
                } else if (EPI == 1 || EPI == 3) {
                    out0[(size_t)n * 512 + m] = f2bf(c);
                } else if (EPI == 2) {
                    int b = n >> 10, t = n & 1023, h = m >> 6, d = m & 63;
                    out0[(((size_t)((b * 8 + h) * 64 + d)) << 10) + t] = f2bf(c);
                } else {
                    fout[(size_t)n * 512 + m] = c;
                }
            }
        }
    }
}

// ---------------------------------------------------------------------------
// Fused rel-attention. Grid: (ublk=16, h=8, b=8). 256 threads = 4 waves,
// each wave owns 16 query rows, full t sweep (independent online softmax).
// Phase 1: bd strip [65][1024] (rows u0..u0+64) in LDS via MFMA vs ph.
// Phase 2: flash sweep, t-tiles of 32.
// rel_shift semantics: bd_shift[u,t] = t<=u ? bd[u, t+1023-u]
//                                    : (t==u+1 ? 0 : bd[u+1, t-u-2])
// ---------------------------------------------------------------------------
__global__ __launch_bounds__(256) void attn_kernel(
    const unsigned short* __restrict__ qu, const unsigned short* __restrict__ qv,
    const unsigned short* __restrict__ kh, const unsigned short* __restrict__ vT,
    const unsigned short* __restrict__ ph, const int* __restrict__ mask,
    unsigned short* __restrict__ xout)
{
    const int ublk = blockIdx.x, h = blockIdx.y, b = blockIdx.z;
    const int u0 = ublk * 64;
    __shared__ unsigned short strip[65][1024]; // 133,120 B
    __shared__ unsigned short Ks[32][72];      // K tile [t][d], padded
    __shared__ unsigned short Vs[64][40];      // V^T tile [d][t], padded
    __shared__ unsigned short Ps[4][16][40];   // per-wave P [u][t], padded
    const int tid = threadIdx.x, lane = tid & 63, wave = tid >> 6;
    const int lrow = lane & 15, lkg = lane >> 4;
    const f32x4 zero = {0.f, 0.f, 0.f, 0.f};

    // ---- Phase 1: bd strip ----
    {
        const unsigned short* qvb = qv + ((size_t)(b * 1024 + u0 + wave * 16 + lrow)) * 512 + h * 64;
        bf16x8 av0 = *(const bf16x8*)(qvb + lkg * 8);
        bf16x8 av1 = *(const bf16x8*)(qvb + 32 + lkg * 8);
        int er = u0 + 64 + lrow; if (er > 1023) er = 1023;  // clamp (row 64 unused for ublk=15)
        const unsigned short* qve = qv + ((size_t)(b * 1024 + er)) * 512 + h * 64;
        bf16x8 ae0 = *(const bf16x8*)(qve + lkg * 8);
        bf16x8 ae1 = *(const bf16x8*)(qve + 32 + lkg * 8);

#pragma unroll 4
        for (int pt = 0; pt < 64; ++pt) {       // own 16 rows x all 1024 p
            int p = pt * 16 + lrow;
            const unsigned short* pb = ph + (size_t)p * 512 + h * 64;
            bf16x8 b0 = *(const bf16x8*)(pb + lkg * 8);
            bf16x8 b1 = *(const bf16x8*)(pb + 32 + lkg * 8);
            f32x4 c = mfma16(av1, b1, mfma16(av0, b0, zero));
#pragma unroll
            for (int q = 0; q < 4; ++q)
                strip[wave * 16 + lkg * 4 + q][pt * 16 + lrow] = f2bf(c[q]);
        }
#pragma unroll 4
        for (int pt = 0; pt < 16; ++pt) {       // extra row u0+64, p split by wave
            int p = wave * 256 + pt * 16 + lrow;
            const unsigned short* pb = ph + (size_t)p * 512 + h * 64;
            bf16x8 b0 = *(const bf16x8*)(pb + lkg * 8);
            bf16x8 b1 = *(const bf16x8*)(pb + 32 + lkg * 8);
            f32x4 c = mfma16(ae1, b1, mfma16(ae0, b0, zero));
            if (lane < 16) strip[64][p] = f2bf(c[0]);   // only output row 0 (= row u0+64)
        }
    }
    __syncthreads();

    // ---- Phase 2: flash sweep ----
    const unsigned short* qub = qu + ((size_t)(b * 1024 + u0 + wave * 16 + lrow)) * 512 + h * 64;
    bf16x8 au0 = *(const bf16x8*)(qub + lkg * 8);
    bf16x8 au1 = *(const bf16x8*)(qub + 32 + lkg * 8);

    f32x4 acc[4];
#pragma unroll
    for (int jj = 0; jj < 4; ++jj) acc[jj] = zero;
    float mrow[4], lsum[4];
#pragma unroll
    for (int q = 0; q < 4; ++q) { mrow[q] = -3.0e38f; lsum[q] = 0.f; }
    const int urow_base = u0 + wave * 16 + lkg * 4;

    for (int t0 = 0; t0 < 1024; t0 += 32) {
        __syncthreads();
        { // stage K tile 32x64
            int r = tid >> 3, d0 = (tid & 7) * 8;
            *(ushort8v*)&Ks[r][d0] =
                *(const ushort8v*)(kh + ((size_t)(b * 1024 + t0 + r)) * 512 + h * 64 + d0);
        }
        { // stage V^T tile 64x32
            int d = tid >> 2, tt = (tid & 3) * 8;
            *(ushort8v*)&Vs[d][tt] =
                *(const ushort8v*)(vT + (((size_t)((b * 8 + h) * 64 + d)) << 10) + t0 + tt);
        }
        __syncthreads();

        f32x4 s[2];
#pragma unroll
        for (int j = 0; j < 2; ++j) {
            bf16x8 k0 = *(const bf16x8*)&Ks[j * 16 + lrow][lkg * 8];
            bf16x8 k1 = *(const bf16x8*)&Ks[j * 16 + lrow][32 + lkg * 8];
            s[j] = mfma16(au1, k1, mfma16(au0, k0, zero));
        }
        // bd + scale + mask
#pragma unroll
        for (int j = 0; j < 2; ++j) {
            int t = t0 + j * 16 + lrow;
#pragma unroll
            for (int q = 0; q < 4; ++q) {
                int u = urow_base + q;
                float bd;
                if (t <= u)          bd = bf2f(strip[u - u0][1023 + t - u]);
                else if (t == u + 1) bd = 0.f;
                else                 bd = bf2f(strip[u - u0 + 1][t - u - 2]);
                float sv = (s[j][q] + bd) * 0.125f;
                if (mask[((size_t)(b * 1024 + u) << 10) + t] == 0) sv = -1.0e30f;
                s[j][q] = sv;
            }
        }
        // online softmax (row stats across 16 lanes of each group)
        float rmx[4];
#pragma unroll
        for (int q = 0; q < 4; ++q) rmx[q] = fmaxf(s[0][q], s[1][q]);
#pragma unroll
        for (int off = 1; off < 16; off <<= 1)
#pragma unroll
            for (int q = 0; q < 4; ++q) rmx[q] = fmaxf(rmx[q], __shfl_xor(rmx[q], off));
        float p0[4], p1[4], fr[4], psum[4];
#pragma unroll
        for (int q = 0; q < 4; ++q) {
            float mn = fmaxf(mrow[q], rmx[q]);
            fr[q] = __expf(mrow[q] - mn);
            mrow[q] = mn;
            p0[q] = __expf(s[0][q] - mn);
            p1[q] = __expf(s[1][q] - mn);
            psum[q] = p0[q] + p1[q];
        }
#pragma unroll
        for (int off = 1; off < 16; off <<= 1)
#pragma unroll
            for (int q = 0; q < 4; ++q) psum[q] += __shfl_xor(psum[q], off);
#pragma unroll
        for (int q = 0; q < 4; ++q) lsum[q] = lsum[q] * fr[q] + psum[q];
#pragma unroll
        for (int jj = 0; jj < 4; ++jj)
#pragma unroll
            for (int q = 0; q < 4; ++q) acc[jj][q] *= fr[q];
        // P -> LDS (bf16), wave-private
#pragma unroll
        for (int q = 0; q < 4; ++q) {
            Ps[wave][lkg * 4 + q][lrow]      = f2bf(p0[q]);
            Ps[wave][lkg * 4 + q][16 + lrow] = f2bf(p1[q]);
        }
        bf16x8 pa = *(const bf16x8*)&Ps[wave][lrow][lkg * 8];
#pragma unroll
        for (int jj = 0; jj < 4; ++jj) {
            bf16x8 vb = *(const bf16x8*)&Vs[jj * 16 + lrow][lkg * 8];
            acc[jj] = mfma16(pa, vb, acc[jj]);
        }
    }

    // epilogue
#pragma unroll
    for (int jj = 0; jj < 4; ++jj) {
#pragma unroll
        for (int q = 0; q < 4; ++q) {
            int u = urow_base + q, d = jj * 16 + lrow;
            float val = acc[jj][q] / lsum[q];
            xout[((size_t)(b * 1024 + u)) * 512 + h * 64 + d] = f2bf(val);
        }
    }
}

// ---------------------------------------------------------------------------
extern "C" void kernel_launch(void* const* d_in, const int* in_sizes, int n_in,
                              void* d_out, int out_size, void* d_ws, size_t ws_size,
                              hipStream_t stream) {
    const float* q    = (const float*)d_in[0];
    const float* k    = (const float*)d_in[1];
    const float* v    = (const float*)d_in[2];
    const float* pos  = (const float*)d_in[3];
    const int*   mask = (const int*)d_in[4];
    const float* Wq   = (const float*)d_in[5];
    const float* bq   = (const float*)d_in[6];
    const float* Wk   = (const float*)d_in[7];
    const float* bk   = (const float*)d_in[8];
    const float* Wv   = (const float*)d_in[9];
    const float* bv   = (const float*)d_in[10];
    const float* Wo   = (const float*)d_in[11];
    const float* bo   = (const float*)d_in[12];
    const float* Wp   = (const float*)d_in[13];
    const float* bias_u = (const float*)d_in[14];
    const float* bias_v = (const float*)d_in[15];
    float* out = (float*)d_out;

    // ws layout (bf16 elements)
    unsigned short* ws = (unsigned short*)d_ws;
    constexpr size_t NQ = (size_t)Bc * Tc * Dc;        // 4,194,304
    unsigned short* ws_qu = ws;
    unsigned short* ws_qv = ws_qu + NQ;
    unsigned short* ws_kh = ws_qv + NQ;
    unsigned short* ws_vT = ws_kh + NQ;                // [b,h,d,t]
    unsigned short* ws_ph = ws_vT + NQ;                // [t, h*64+d]
    unsigned short* ws_x  = ws_ph + (size_t)Tc * Dc;   // attention out, bf16
    // total: 42,991,616 bytes

    dim3 blk(256);
    dim3 gproj(64, 4);
    gemm_nt<0, true><<<gproj, blk, 0, stream>>>(q, Wq, bq, bias_u, bias_v, ws_qu, ws_qv, nullptr);
    gemm_nt<1, true><<<gproj, blk, 0, stream>>>(k, Wk, bk, nullptr, nullptr, ws_kh, nullptr, nullptr);
    gemm_nt<2, true><<<gproj, blk, 0, stream>>>(v, Wv, bv, nullptr, nullptr, ws_vT, nullptr, nullptr);
    gemm_nt<3, true><<<dim3(8, 4), blk, 0, stream>>>(pos, Wp, nullptr, nullptr, nullptr, ws_ph, nullptr, nullptr);
    attn_kernel<<<dim3(16, 8, 8), blk, 0, stream>>>(ws_qu, ws_qv, ws_kh, ws_vT, ws_ph, mask, ws_x);
    gemm_nt<4, false><<<gproj, blk, 0, stream>>>(ws_x, Wo, bo, nullptr, nullptr, nullptr, nullptr, out);
}

// Round 2
// 286.297 us; speedup vs baseline: 1.5131x; 1.5131x over previous
//
#include <hip/hip_runtime.h>
#include <stdint.h>

// Problem constants (B=8, T=1024, D=512, H=8, dk=64)
#define Bc 8
#define Tc 1024
#define Dc 512
#define Hc 8

typedef __bf16 bf16x8 __attribute__((ext_vector_type(8)));
typedef float f32x4 __attribute__((ext_vector_type(4)));
typedef unsigned short ushort8v __attribute__((ext_vector_type(8)));

__device__ __forceinline__ unsigned short f2bf(float f) {
    union { float f; uint32_t u; } v; v.f = f;
    uint32_t u = v.u;
    u += 0x7fffu + ((u >> 16) & 1u);   // RNE
    return (unsigned short)(u >> 16);
}
__device__ __forceinline__ float bf2f(unsigned short s) {
    union { uint32_t u; float f; } v; v.u = ((uint32_t)s) << 16;
    return v.f;
}
__device__ __forceinline__ f32x4 mfma16(bf16x8 a, bf16x8 b, f32x4 c) {
    return __builtin_amdgcn_mfma_f32_16x16x32_bf16(a, b, c, 0, 0, 0);
}

// ---------------------------------------------------------------------------
// mask int32 [8*1024][1024] -> bit-packed [8*1024][32] uint32 (bit=1 => live)
// ---------------------------------------------------------------------------
__global__ __launch_bounds__(256) void pack_mask(const int* __restrict__ mask,
                                                 uint32_t* __restrict__ bits)
{
    int wid = (blockIdx.x * 256 + threadIdx.x) >> 6;   // wave id, 131072 total
    int lane = threadIdx.x & 63;
    size_t base = (size_t)wid * 64;
    unsigned long long bl = __ballot(mask[base + lane] != 0);
    if (lane == 0)  bits[wid * 2]     = (uint32_t)bl;
    if (lane == 32) bits[wid * 2 + 1] = (uint32_t)(bl >> 32);
}

// ---------------------------------------------------------------------------
// Generic GEMM: C[n,m] = sum_k A[n,k] * W[m,k].  Grid: (m-tiles, n-tiles) so
// consecutive blocks share the A panel (L2 reuse).
// EPI: 0 qu/qv pair  1 C+bias  2 C+bias transposed [b,h,d,t]  3 C  4 fp32 out
// ---------------------------------------------------------------------------
template<int EPI, bool AF32>
__global__ __launch_bounds__(256) void gemm_nt(
    const void* __restrict__ Ap, const float* __restrict__ Wmat,
    const float* __restrict__ bias,
    const float* __restrict__ bias_u, const float* __restrict__ bias_v,
    unsigned short* __restrict__ out0, unsigned short* __restrict__ out1,
    float* __restrict__ fout)
{
    const int n0 = blockIdx.y * 128, m0 = blockIdx.x * 128;
    __shared__ unsigned short As[128][72];
    __shared__ unsigned short Bs[128][72];
    const int tid = threadIdx.x, lane = tid & 63, wave = tid >> 6;
    const int lrow = lane & 15, lkg = lane >> 4;
    const int wr = (wave >> 1) * 64, wc = (wave & 1) * 64;

    f32x4 acc[4][4];
#pragma unroll
    for (int i = 0; i < 4; ++i)
#pragma unroll
        for (int j = 0; j < 4; ++j) acc[i][j] = f32x4{0.f, 0.f, 0.f, 0.f};

    for (int kt = 0; kt < 512; kt += 64) {
        __syncthreads();
#pragma unroll
        for (int it = 0; it < 4; ++it) {
            int c = tid + it * 256;
            int r = c >> 3, kc = (c & 7) * 8;
            if (AF32) {
                const float* src = (const float*)Ap + (size_t)(n0 + r) * 512 + kt + kc;
                ushort8v v;
#pragma unroll
                for (int j = 0; j < 8; ++j) v[j] = f2bf(src[j]);
                *(ushort8v*)&As[r][kc] = v;
            } else {
                const unsigned short* src = (const unsigned short*)Ap + (size_t)(n0 + r) * 512 + kt + kc;
                *(ushort8v*)&As[r][kc] = *(const ushort8v*)src;
            }
            const float* wsrc = Wmat + (size_t)(m0 + r) * 512 + kt + kc;
            ushort8v w;
#pragma unroll
            for (int j = 0; j < 8; ++j) w[j] = f2bf(wsrc[j]);
            *(ushort8v*)&Bs[r][kc] = w;
        }
        __syncthreads();
#pragma unroll
        for (int kk = 0; kk < 2; ++kk) {
            bf16x8 a[4], bb[4];
#pragma unroll
            for (int i = 0; i < 4; ++i)
                a[i] = *(const bf16x8*)&As[wr + i * 16 + lrow][kk * 32 + lkg * 8];
#pragma unroll
            for (int j = 0; j < 4; ++j)
                bb[j] = *(const bf16x8*)&Bs[wc + j * 16 + lrow][kk * 32 + lkg * 8];
#pragma unroll
            for (int i = 0; i < 4; ++i)
#pragma unroll
                for (int j = 0; j < 4; ++j)
                    acc[i][j] = mfma16(a[i], bb[j], acc[i][j]);
        }
    }

#pragma unroll
    for (int i = 0; i < 4; ++i) {
        int nbase = n0 + wr + i * 16 + lkg * 4;
#pragma unroll
        for (int j = 0; j < 4; ++j) {
            int m = m0 + wc + j * 16 + lrow;
            float bb = (EPI == 3) ? 0.f : bias[m];
            float bu = 0.f, bv = 0.f;
            if (EPI == 0) { bu = bias_u[m]; bv = bias_v[m]; }
#pragma unroll
            for (int q = 0; q < 4; ++q) {
                int n = nbase + q;
                float c = acc[i][j][q] + bb;
                if (EPI == 0) {
                    out0[(size_t)n * 512 + m] = f2bf(c + bu);
                    out1[(size_t)n * 512 + m] = f2bf(c + bv);
                } else if (EPI == 1 || EPI == 3) {
                    out0[(size_t)n * 512 + m] = f2bf(c);
                } else if (EPI == 2) {
                    int b = n >> 10, t = n & 1023, h = m >> 6, d = m & 63;
                    out0[(((size_t)((b * 8 + h) * 64 + d)) << 10) + t] = f2bf(c);
                } else {
                    fout[(size_t)n * 512 + m] = c;
                }
            }
        }
    }
}

// ---------------------------------------------------------------------------
// BD GEMM: bd[u,p] = q_v[b,u,h*64:]·ph[p,h*64:], scaled by 0.125, scattered
// through the rel_shift inverse into bds[z][u'][t']:
//   p >= 1023-u : (u, p+u-1023)    else (u>=1): (u-1, p+u+1)   else dropped.
// Diagonal t' = u'+1 is never written (handled as 0 in attn). Grid (8,8,Z).
// ---------------------------------------------------------------------------
__global__ __launch_bounds__(256) void bd_gemm(
    const unsigned short* __restrict__ qv, const unsigned short* __restrict__ ph,
    unsigned short* __restrict__ bds, int bh_base)
{
    const int u0 = blockIdx.x * 128, p0 = blockIdx.y * 128;
    const int bh = bh_base + blockIdx.z;
    const int b = bh >> 3, h = bh & 7;
    __shared__ unsigned short As[128][72];
    __shared__ unsigned short Bs[128][72];
    const int tid = threadIdx.x, lane = tid & 63, wave = tid >> 6;
    const int lrow = lane & 15, lkg = lane >> 4;
    const int wr = (wave >> 1) * 64, wc = (wave & 1) * 64;

#pragma unroll
    for (int it = 0; it < 4; ++it) {
        int c = tid + it * 256;
        int r = c >> 3, kc = (c & 7) * 8;
        *(ushort8v*)&As[r][kc] =
            *(const ushort8v*)(qv + ((size_t)(b * 1024 + u0 + r)) * 512 + h * 64 + kc);
        *(ushort8v*)&Bs[r][kc] =
            *(const ushort8v*)(ph + ((size_t)(p0 + r)) * 512 + h * 64 + kc);
    }
    __syncthreads();

    f32x4 acc[4][4];
#pragma unroll
    for (int i = 0; i < 4; ++i)
#pragma unroll
        for (int j = 0; j < 4; ++j) acc[i][j] = f32x4{0.f, 0.f, 0.f, 0.f};
#pragma unroll
    for (int kk = 0; kk < 2; ++kk) {
        bf16x8 a[4], bb[4];
#pragma unroll
        for (int i = 0; i < 4; ++i)
            a[i] = *(const bf16x8*)&As[wr + i * 16 + lrow][kk * 32 + lkg * 8];
#pragma unroll
        for (int j = 0; j < 4; ++j)
            bb[j] = *(const bf16x8*)&Bs[wc + j * 16 + lrow][kk * 32 + lkg * 8];
#pragma unroll
        for (int i = 0; i < 4; ++i)
#pragma unroll
            for (int j = 0; j < 4; ++j)
                acc[i][j] = mfma16(a[i], bb[j], acc[i][j]);
    }

    unsigned short* dst = bds + ((size_t)blockIdx.z << 20);
#pragma unroll
    for (int i = 0; i < 4; ++i) {
#pragma unroll
        for (int j = 0; j < 4; ++j) {
#pragma unroll
            for (int q = 0; q < 4; ++q) {
                int u = u0 + wr + i * 16 + lkg * 4 + q;
                int p = p0 + wc + j * 16 + lrow;
                unsigned short val = f2bf(acc[i][j][q] * 0.125f);
                if (p >= 1023 - u) {
                    dst[((size_t)u << 10) + (p + u - 1023)] = val;
                } else if (u >= 1) {
                    dst[((size_t)(u - 1) << 10) + (p + u + 1)] = val;
                }
            }
        }
    }
}

// ---------------------------------------------------------------------------
// Lean flash attention. Flat grid (XCD-swizzled when full): block = (b,h,ublk),
// 256 threads = 4 waves x 16 query rows. BD read directly from global (each
// element consumed once); mask bits staged in LDS.
// ---------------------------------------------------------------------------
__global__ __launch_bounds__(256, 4) void attn2(
    const unsigned short* __restrict__ qu, const unsigned short* __restrict__ kh,
    const unsigned short* __restrict__ vT, const unsigned short* __restrict__ bds,
    const uint32_t* __restrict__ mbits, unsigned short* __restrict__ xout,
    int b_base)
{
    int id = blockIdx.x, nid, b, rem;
    if (gridDim.x == 1024) {                // full path: 128 blocks per XCD
        nid = (id & 7) * 128 + (id >> 3);
        b = b_base + (nid >> 7); rem = nid & 127;
    } else {                                // per-batch path: 128 blocks
        nid = (id & 7) * 16 + (id >> 3);
        b = b_base; rem = nid;
    }
    const int h = rem >> 4, ublk = rem & 15;
    const int u0 = ublk * 64;

    __shared__ unsigned short Ks[32][72];
    __shared__ unsigned short Vs[64][40];
    __shared__ unsigned short Ps[4][16][40];
    __shared__ uint32_t Mw[64][32];
    const int tid = threadIdx.x, lane = tid & 63, wave = tid >> 6;
    const int lrow = lane & 15, lkg = lane >> 4;
    const f32x4 zero = {0.f, 0.f, 0.f, 0.f};

    // stage mask words (8KB)
    {
        const uint32_t* src = mbits + ((size_t)(b * 1024 + u0)) * 32;
        ((uint4*)Mw)[tid]       = ((const uint4*)src)[tid];
        ((uint4*)Mw)[tid + 256] = ((const uint4*)src)[tid + 256];
    }

    const unsigned short* qub = qu + ((size_t)(b * 1024 + u0 + wave * 16 + lrow)) * 512 + h * 64;
    bf16x8 au0 = *(const bf16x8*)(qub + lkg * 8);
    bf16x8 au1 = *(const bf16x8*)(qub + 32 + lkg * 8);

    const int urow_base = u0 + wave * 16 + lkg * 4;
    const unsigned short* bdrow[4];
    const int zoff = (b - b_base) * 8 + h;
#pragma unroll
    for (int q = 0; q < 4; ++q)
        bdrow[q] = bds + ((size_t)zoff << 20) + ((size_t)(urow_base + q) << 10);

    f32x4 acc[4];
#pragma unroll
    for (int jj = 0; jj < 4; ++jj) acc[jj] = zero;
    float mrow[4], lsum[4];
#pragma unroll
    for (int q = 0; q < 4; ++q) { mrow[q] = -3.0e38f; lsum[q] = 0.f; }

    for (int t0 = 0; t0 < 1024; t0 += 32) {
        __syncthreads();
        {
            int r = tid >> 3, d0 = (tid & 7) * 8;
            *(ushort8v*)&Ks[r][d0] =
                *(const ushort8v*)(kh + ((size_t)(b * 1024 + t0 + r)) * 512 + h * 64 + d0);
        }
        {
            int d = tid >> 2, tt = (tid & 3) * 8;
            *(ushort8v*)&Vs[d][tt] =
                *(const ushort8v*)(vT + (((size_t)((b * 8 + h) * 64 + d)) << 10) + t0 + tt);
        }
        // BD + mask for this tile (global / LDS reads overlap the staging)
        float bdv[2][4];
        uint32_t mw[4];
#pragma unroll
        for (int q = 0; q < 4; ++q) {
            int u = urow_base + q;
#pragma unroll
            for (int j = 0; j < 2; ++j) {
                int t = t0 + j * 16 + lrow;
                float v = bf2f(bdrow[q][t]);
                bdv[j][q] = (t == u + 1) ? 0.f : v;
            }
        }
        __syncthreads();
#pragma unroll
        for (int q = 0; q < 4; ++q)
            mw[q] = Mw[urow_base + q - u0][t0 >> 5];

        f32x4 s[2];
#pragma unroll
        for (int j = 0; j < 2; ++j) {
            bf16x8 k0 = *(const bf16x8*)&Ks[j * 16 + lrow][lkg * 8];
            bf16x8 k1 = *(const bf16x8*)&Ks[j * 16 + lrow][32 + lkg * 8];
            s[j] = mfma16(au1, k1, mfma16(au0, k0, zero));
        }
#pragma unroll
        for (int j = 0; j < 2; ++j) {
#pragma unroll
            for (int q = 0; q < 4; ++q) {
                float sv = fmaf(s[j][q], 0.125f, bdv[j][q]);
                if (!((mw[q] >> (j * 16 + lrow)) & 1)) sv = -1.0e30f;
                s[j][q] = sv;
            }
        }
        // online softmax across the 16 lanes of each row group
        float rmx[4];
#pragma unroll
        for (int q = 0; q < 4; ++q) rmx[q] = fmaxf(s[0][q], s[1][q]);
#pragma unroll
        for (int off = 1; off < 16; off <<= 1)
#pragma unroll
            for (int q = 0; q < 4; ++q) rmx[q] = fmaxf(rmx[q], __shfl_xor(rmx[q], off));
        float p0v[4], p1v[4], fr[4], psum[4];
#pragma unroll
        for (int q = 0; q < 4; ++q) {
            float mn = fmaxf(mrow[q], rmx[q]);
            fr[q] = __expf(mrow[q] - mn);
            mrow[q] = mn;
            p0v[q] = __expf(s[0][q] - mn);
            p1v[q] = __expf(s[1][q] - mn);
            psum[q] = p0v[q] + p1v[q];
        }
#pragma unroll
        for (int off = 1; off < 16; off <<= 1)
#pragma unroll
            for (int q = 0; q < 4; ++q) psum[q] += __shfl_xor(psum[q], off);
#pragma unroll
        for (int q = 0; q < 4; ++q) lsum[q] = lsum[q] * fr[q] + psum[q];
#pragma unroll
        for (int jj = 0; jj < 4; ++jj)
#pragma unroll
            for (int q = 0; q < 4; ++q) acc[jj][q] *= fr[q];
#pragma unroll
        for (int q = 0; q < 4; ++q) {
            Ps[wave][lkg * 4 + q][lrow]      = f2bf(p0v[q]);
            Ps[wave][lkg * 4 + q][16 + lrow] = f2bf(p1v[q]);
        }
        bf16x8 pa = *(const bf16x8*)&Ps[wave][lrow][lkg * 8];
#pragma unroll
        for (int jj = 0; jj < 4; ++jj) {
            bf16x8 vb = *(const bf16x8*)&Vs[jj * 16 + lrow][lkg * 8];
            acc[jj] = mfma16(pa, vb, acc[jj]);
        }
    }

#pragma unroll
    for (int jj = 0; jj < 4; ++jj) {
#pragma unroll
        for (int q = 0; q < 4; ++q) {
            int u = urow_base + q, d = jj * 16 + lrow;
            float val = acc[jj][q] / lsum[q];
            xout[((size_t)(b * 1024 + u)) * 512 + h * 64 + d] = f2bf(val);
        }
    }
}

// ---------------------------------------------------------------------------
extern "C" void kernel_launch(void* const* d_in, const int* in_sizes, int n_in,
                              void* d_out, int out_size, void* d_ws, size_t ws_size,
                              hipStream_t stream) {
    const float* q    = (const float*)d_in[0];
    const float* k    = (const float*)d_in[1];
    const float* v    = (const float*)d_in[2];
    const float* pos  = (const float*)d_in[3];
    const int*   mask = (const int*)d_in[4];
    const float* Wq   = (const float*)d_in[5];
    const float* bq   = (const float*)d_in[6];
    const float* Wk   = (const float*)d_in[7];
    const float* bk   = (const float*)d_in[8];
    const float* Wv   = (const float*)d_in[9];
    const float* bv   = (const float*)d_in[10];
    const float* Wo   = (const float*)d_in[11];
    const float* bo   = (const float*)d_in[12];
    const float* Wp   = (const float*)d_in[13];
    const float* bias_u = (const float*)d_in[14];
    const float* bias_v = (const float*)d_in[15];
    float* out = (float*)d_out;

    unsigned short* ws = (unsigned short*)d_ws;
    constexpr size_t NQ = (size_t)Bc * Tc * Dc;          // 4,194,304 elems
    constexpr size_t NP = (size_t)Tc * Dc;               // 524,288
    constexpr size_t NMB = (size_t)Bc * Tc * 32;         // 262,144 words
    unsigned short* ws_qu = ws;
    unsigned short* ws_qv = ws_qu + NQ;
    unsigned short* ws_kh = ws_qv + NQ;
    unsigned short* ws_vT = ws_kh + NQ;
    unsigned short* ws_ph = ws_vT + NQ;
    uint32_t*       ws_mb = (uint32_t*)(ws_ph + NP);
    unsigned short* ws_bd = (unsigned short*)(ws_mb + NMB);

    constexpr size_t BD_FULL  = (size_t)64 * 1024 * 1024;   // elems
    constexpr size_t BD_SMALL = (size_t)8 * 1024 * 1024;
    const size_t base_bytes = (size_t)(4 * NQ + NP) * 2 + NMB * 4;
    const bool full = ws_size >= base_bytes + BD_FULL * 2;           // ~170 MB
    const bool tier2 = !full && ws_size >= base_bytes + (BD_SMALL + NQ) * 2;

    dim3 blk(256);
    pack_mask<<<32768, blk, 0, stream>>>(mask, ws_mb);
    gemm_nt<0, true><<<dim3(4, 64), blk, 0, stream>>>(q, Wq, bq, bias_u, bias_v, ws_qu, ws_qv, nullptr);
    gemm_nt<1, true><<<dim3(4, 64), blk, 0, stream>>>(k, Wk, bk, nullptr, nullptr, ws_kh, nullptr, nullptr);
    gemm_nt<2, true><<<dim3(4, 64), blk, 0, stream>>>(v, Wv, bv, nullptr, nullptr, ws_vT, nullptr, nullptr);
    gemm_nt<3, true><<<dim3(4, 8), blk, 0, stream>>>(pos, Wp, nullptr, nullptr, nullptr, ws_ph, nullptr, nullptr);

    if (full) {
        unsigned short* ws_x = ws_qv;  // overlay: qv dead after bd_gemm
        bd_gemm<<<dim3(8, 8, 64), blk, 0, stream>>>(ws_qv, ws_ph, ws_bd, 0);
        attn2<<<dim3(1024), blk, 0, stream>>>(ws_qu, ws_kh, ws_vT, ws_bd, ws_mb, ws_x, 0);
        gemm_nt<4, false><<<dim3(4, 64), blk, 0, stream>>>(ws_x, Wo, bo, nullptr, nullptr, nullptr, nullptr, out);
    } else if (tier2) {
        unsigned short* ws_x = ws_bd + BD_SMALL;
        for (int b = 0; b < 8; ++b) {
            bd_gemm<<<dim3(8, 8, 8), blk, 0, stream>>>(ws_qv, ws_ph, ws_bd, b * 8);
            attn2<<<dim3(128), blk, 0, stream>>>(ws_qu, ws_kh, ws_vT, ws_bd, ws_mb, ws_x, b);
        }
        gemm_nt<4, false><<<dim3(4, 64), blk, 0, stream>>>(ws_x, Wo, bo, nullptr, nullptr, nullptr, nullptr, out);
    }
    // if neither tier fits, nothing is launched -> loud failure tells us ws_size
}

// Round 3
// 211.999 us; speedup vs baseline: 2.0434x; 1.3505x over previous
//
#include <hip/hip_runtime.h>
#include <stdint.h>

// Problem constants (B=8, T=1024, D=512, H=8, dk=64)
#define Bc 8
#define Tc 1024
#define Dc 512
#define Hc 8

typedef __bf16 bf16x8 __attribute__((ext_vector_type(8)));
typedef float f32x4 __attribute__((ext_vector_type(4)));
typedef unsigned short ushort8v __attribute__((ext_vector_type(8)));

__device__ __forceinline__ unsigned short f2bf(float f) {
    union { float f; uint32_t u; } v; v.f = f;
    uint32_t u = v.u;
    u += 0x7fffu + ((u >> 16) & 1u);   // RNE
    return (unsigned short)(u >> 16);
}
__device__ __forceinline__ float bf2f(unsigned short s) {
    union { uint32_t u; float f; } v; v.u = ((uint32_t)s) << 16;
    return v.f;
}
__device__ __forceinline__ unsigned short f2bf_native(float f) {
    __bf16 b = (__bf16)f;
    return *(unsigned short*)&b;
}
__device__ __forceinline__ f32x4 mfma16(bf16x8 a, bf16x8 b, f32x4 c) {
    return __builtin_amdgcn_mfma_f32_16x16x32_bf16(a, b, c, 0, 0, 0);
}

// ---------------------------------------------------------------------------
// pack_prep: blocks < 32768 bit-pack the mask; blocks >= 32768 convert the 5
// weight matrices (Wq,Wk,Wv,Wp,Wo) to bf16 (done once, not 64x per GEMM block)
// ---------------------------------------------------------------------------
__global__ __launch_bounds__(256) void pack_prep(
    const int* __restrict__ mask, uint32_t* __restrict__ bits,
    const float* __restrict__ Wq, const float* __restrict__ Wk,
    const float* __restrict__ Wv, const float* __restrict__ Wp,
    const float* __restrict__ Wo, unsigned short* __restrict__ Wb)
{
    int bid = blockIdx.x;
    if (bid < 32768) {
        int wid = (bid * 256 + threadIdx.x) >> 6;
        int lane = threadIdx.x & 63;
        unsigned long long bl = __ballot(mask[(size_t)wid * 64 + lane] != 0);
        if (lane == 0)  bits[wid * 2]     = (uint32_t)bl;
        if (lane == 32) bits[wid * 2 + 1] = (uint32_t)(bl >> 32);
    } else {
        int i = (bid - 32768) * 2048 + threadIdx.x * 8;   // 640 blocks, 1,310,720 elems
        int m = i >> 18, r = i & 262143;
        const float* Ws[5] = {Wq, Wk, Wv, Wp, Wo};
        const float* s = Ws[m] + r;
        ushort8v o;
#pragma unroll
        for (int j = 0; j < 8; ++j) o[j] = f2bf(s[j]);
        *(ushort8v*)(Wb + i) = o;
    }
}

// ---------------------------------------------------------------------------
// Fused projections: z=0 Q->(qu,qv), z=1 K->kh, z=2 V->vT, z=3 pos->ph.
// C[n,m] = sum_k A[n,k]*W[m,k]; A f32 (converted in staging), W bf16 (prep'd).
// ---------------------------------------------------------------------------
__global__ __launch_bounds__(256) void proj4(
    const float* __restrict__ qin, const float* __restrict__ kin,
    const float* __restrict__ vin, const float* __restrict__ pin,
    const unsigned short* __restrict__ Wb,
    const float* __restrict__ bq, const float* __restrict__ bk,
    const float* __restrict__ bv,
    const float* __restrict__ bias_u, const float* __restrict__ bias_v,
    unsigned short* __restrict__ qu, unsigned short* __restrict__ qv,
    unsigned short* __restrict__ kh, unsigned short* __restrict__ vT,
    unsigned short* __restrict__ ph)
{
    const int z = blockIdx.z;
    if (z == 3 && blockIdx.y >= 8) return;
    const float* A = z == 0 ? qin : z == 1 ? kin : z == 2 ? vin : pin;
    const unsigned short* W = Wb + (size_t)z * 262144;

    const int n0 = blockIdx.y * 128, m0 = blockIdx.x * 128;
    __shared__ unsigned short As[128][72];
    __shared__ unsigned short Bs[128][72];
    const int tid = threadIdx.x, lane = tid & 63, wave = tid >> 6;
    const int lrow = lane & 15, lkg = lane >> 4;
    const int wr = (wave >> 1) * 64, wc = (wave & 1) * 64;

    f32x4 acc[4][4];
#pragma unroll
    for (int i = 0; i < 4; ++i)
#pragma unroll
        for (int j = 0; j < 4; ++j) acc[i][j] = f32x4{0.f, 0.f, 0.f, 0.f};

    for (int kt = 0; kt < 512; kt += 64) {
        __syncthreads();
#pragma unroll
        for (int it = 0; it < 4; ++it) {
            int c = tid + it * 256;
            int r = c >> 3, kc = (c & 7) * 8;
            const float* src = A + (size_t)(n0 + r) * 512 + kt + kc;
            ushort8v v;
#pragma unroll
            for (int j = 0; j < 8; ++j) v[j] = f2bf(src[j]);
            *(ushort8v*)&As[r][kc] = v;
            *(ushort8v*)&Bs[r][kc] =
                *(const ushort8v*)(W + (size_t)(m0 + r) * 512 + kt + kc);
        }
        __syncthreads();
#pragma unroll
        for (int kk = 0; kk < 2; ++kk) {
            bf16x8 a[4], bb[4];
#pragma unroll
            for (int i = 0; i < 4; ++i)
                a[i] = *(const bf16x8*)&As[wr + i * 16 + lrow][kk * 32 + lkg * 8];
#pragma unroll
            for (int j = 0; j < 4; ++j)
                bb[j] = *(const bf16x8*)&Bs[wc + j * 16 + lrow][kk * 32 + lkg * 8];
#pragma unroll
            for (int i = 0; i < 4; ++i)
#pragma unroll
                for (int j = 0; j < 4; ++j)
                    acc[i][j] = mfma16(a[i], bb[j], acc[i][j]);
        }
    }

#pragma unroll
    for (int i = 0; i < 4; ++i) {
        int nbase = n0 + wr + i * 16 + lkg * 4;
#pragma unroll
        for (int j = 0; j < 4; ++j) {
            int m = m0 + wc + j * 16 + lrow;
            float bb = z == 0 ? bq[m] : z == 1 ? bk[m] : z == 2 ? bv[m] : 0.f;
            float bu = 0.f, bvv = 0.f;
            if (z == 0) { bu = bias_u[m]; bvv = bias_v[m]; }
#pragma unroll
            for (int q = 0; q < 4; ++q) {
                int n = nbase + q;
                float c = acc[i][j][q] + bb;
                if (z == 0) {
                    qu[(size_t)n * 512 + m] = f2bf(c + bu);
                    qv[(size_t)n * 512 + m] = f2bf(c + bvv);
                } else if (z == 1) {
                    kh[(size_t)n * 512 + m] = f2bf(c);
                } else if (z == 2) {
                    int b = n >> 10, t = n & 1023, h = m >> 6, d = m & 63;
                    vT[(((size_t)((b * 8 + h) * 64 + d)) << 10) + t] = f2bf(c);
                } else {
                    ph[(size_t)n * 512 + m] = f2bf(c);
                }
            }
        }
    }
}

// ---------------------------------------------------------------------------
// Final output GEMM: out[n,m] = x[n,:]·Wo[m,:] + bo (fp32 out, x bf16, Wo bf16)
// ---------------------------------------------------------------------------
__global__ __launch_bounds__(256) void gemm_out(
    const unsigned short* __restrict__ X, const unsigned short* __restrict__ Wob,
    const float* __restrict__ bo, float* __restrict__ fout)
{
    const int n0 = blockIdx.y * 128, m0 = blockIdx.x * 128;
    __shared__ unsigned short As[128][72];
    __shared__ unsigned short Bs[128][72];
    const int tid = threadIdx.x, lane = tid & 63, wave = tid >> 6;
    const int lrow = lane & 15, lkg = lane >> 4;
    const int wr = (wave >> 1) * 64, wc = (wave & 1) * 64;

    f32x4 acc[4][4];
#pragma unroll
    for (int i = 0; i < 4; ++i)
#pragma unroll
        for (int j = 0; j < 4; ++j) acc[i][j] = f32x4{0.f, 0.f, 0.f, 0.f};

    for (int kt = 0; kt < 512; kt += 64) {
        __syncthreads();
#pragma unroll
        for (int it = 0; it < 4; ++it) {
            int c = tid + it * 256;
            int r = c >> 3, kc = (c & 7) * 8;
            *(ushort8v*)&As[r][kc] =
                *(const ushort8v*)(X + (size_t)(n0 + r) * 512 + kt + kc);
            *(ushort8v*)&Bs[r][kc] =
                *(const ushort8v*)(Wob + (size_t)(m0 + r) * 512 + kt + kc);
        }
        __syncthreads();
#pragma unroll
        for (int kk = 0; kk < 2; ++kk) {
            bf16x8 a[4], bb[4];
#pragma unroll
            for (int i = 0; i < 4; ++i)
                a[i] = *(const bf16x8*)&As[wr + i * 16 + lrow][kk * 32 + lkg * 8];
#pragma unroll
            for (int j = 0; j < 4; ++j)
                bb[j] = *(const bf16x8*)&Bs[wc + j * 16 + lrow][kk * 32 + lkg * 8];
#pragma unroll
            for (int i = 0; i < 4; ++i)
#pragma unroll
                for (int j = 0; j < 4; ++j)
                    acc[i][j] = mfma16(a[i], bb[j], acc[i][j]);
        }
    }
#pragma unroll
    for (int i = 0; i < 4; ++i) {
        int nbase = n0 + wr + i * 16 + lkg * 4;
#pragma unroll
        for (int j = 0; j < 4; ++j) {
            int m = m0 + wc + j * 16 + lrow;
            float bb = bo[m];
#pragma unroll
            for (int q = 0; q < 4; ++q)
                fout[(size_t)(nbase + q) * 512 + m] = acc[i][j][q] + bb;
        }
    }
}

// ---------------------------------------------------------------------------
// BD GEMM: bd[u,p] = q_v·ph scaled by 0.125, scattered through rel_shift
// inverse into bds[z][u'][t'] (diagonal t'=u'+1 left unwritten => 0 in attn).
// ---------------------------------------------------------------------------
__global__ __launch_bounds__(256) void bd_gemm(
    const unsigned short* __restrict__ qv, const unsigned short* __restrict__ ph,
    unsigned short* __restrict__ bds, int bh_base)
{
    const int u0 = blockIdx.x * 128, p0 = blockIdx.y * 128;
    const int bh = bh_base + blockIdx.z;
    const int b = bh >> 3, h = bh & 7;
    __shared__ unsigned short As[128][72];
    __shared__ unsigned short Bs[128][72];
    const int tid = threadIdx.x, lane = tid & 63, wave = tid >> 6;
    const int lrow = lane & 15, lkg = lane >> 4;
    const int wr = (wave >> 1) * 64, wc = (wave & 1) * 64;

#pragma unroll
    for (int it = 0; it < 4; ++it) {
        int c = tid + it * 256;
        int r = c >> 3, kc = (c & 7) * 8;
        *(ushort8v*)&As[r][kc] =
            *(const ushort8v*)(qv + ((size_t)(b * 1024 + u0 + r)) * 512 + h * 64 + kc);
        *(ushort8v*)&Bs[r][kc] =
            *(const ushort8v*)(ph + ((size_t)(p0 + r)) * 512 + h * 64 + kc);
    }
    __syncthreads();

    f32x4 acc[4][4];
#pragma unroll
    for (int i = 0; i < 4; ++i)
#pragma unroll
        for (int j = 0; j < 4; ++j) acc[i][j] = f32x4{0.f, 0.f, 0.f, 0.f};
#pragma unroll
    for (int kk = 0; kk < 2; ++kk) {
        bf16x8 a[4], bb[4];
#pragma unroll
        for (int i = 0; i < 4; ++i)
            a[i] = *(const bf16x8*)&As[wr + i * 16 + lrow][kk * 32 + lkg * 8];
#pragma unroll
        for (int j = 0; j < 4; ++j)
            bb[j] = *(const bf16x8*)&Bs[wc + j * 16 + lrow][kk * 32 + lkg * 8];
#pragma unroll
        for (int i = 0; i < 4; ++i)
#pragma unroll
            for (int j = 0; j < 4; ++j)
                acc[i][j] = mfma16(a[i], bb[j], acc[i][j]);
    }

    unsigned short* dst = bds + ((size_t)blockIdx.z << 20);
#pragma unroll
    for (int i = 0; i < 4; ++i) {
#pragma unroll
        for (int j = 0; j < 4; ++j) {
#pragma unroll
            for (int q = 0; q < 4; ++q) {
                int u = u0 + wr + i * 16 + lkg * 4 + q;
                int p = p0 + wc + j * 16 + lrow;
                unsigned short val = f2bf(acc[i][j][q] * 0.125f);
                if (p >= 1023 - u) {
                    dst[((size_t)u << 10) + (p + u - 1023)] = val;
                } else if (u >= 1) {
                    dst[((size_t)(u - 1) << 10) + (p + u + 1)] = val;
                }
            }
        }
    }
}

// ---------------------------------------------------------------------------
// Flash attention, KVBLK=64, per-lane lsum, defer-max (THR=8).
// 4 waves x 16 query rows per block; 16 t-tiles of 64.
// ---------------------------------------------------------------------------
__global__ __launch_bounds__(256, 4) void attn3(
    const unsigned short* __restrict__ qu, const unsigned short* __restrict__ kh,
    const unsigned short* __restrict__ vT, const unsigned short* __restrict__ bds,
    const uint32_t* __restrict__ mbits, unsigned short* __restrict__ xout,
    int b_base)
{
    int id = blockIdx.x, nid, b, rem;
    if (gridDim.x == 1024) {
        nid = (id & 7) * 128 + (id >> 3);
        b = b_base + (nid >> 7); rem = nid & 127;
    } else {
        nid = (id & 7) * 16 + (id >> 3);
        b = b_base; rem = nid;
    }
    const int h = rem >> 4, ublk = rem & 15;
    const int u0 = ublk * 64;

    __shared__ unsigned short Ks[64][72];
    __shared__ unsigned short Vs[64][72];
    __shared__ unsigned short Ps[4][16][72];
    __shared__ uint32_t Mw[64][32];
    const int tid = threadIdx.x, lane = tid & 63, wave = tid >> 6;
    const int lrow = lane & 15, lkg = lane >> 4;
    const f32x4 zero = {0.f, 0.f, 0.f, 0.f};

    { // stage mask words (8KB), visible after first loop sync
        const uint32_t* src = mbits + ((size_t)(b * 1024 + u0)) * 32;
        ((uint4*)Mw)[tid]       = ((const uint4*)src)[tid];
        ((uint4*)Mw)[tid + 256] = ((const uint4*)src)[tid + 256];
    }

    const unsigned short* qub = qu + ((size_t)(b * 1024 + u0 + wave * 16 + lrow)) * 512 + h * 64;
    bf16x8 au0 = *(const bf16x8*)(qub + lkg * 8);
    bf16x8 au1 = *(const bf16x8*)(qub + 32 + lkg * 8);

    const int urow = u0 + wave * 16 + lkg * 4;           // +q
    const int zoff = (b - b_base) * 8 + h;
    const unsigned short* bdb = bds + ((size_t)zoff << 20);
    const unsigned short* kbase = kh + ((size_t)(b * 1024)) * 512 + h * 64;
    const unsigned short* vbase = vT + (((size_t)((b * 8 + h) * 64)) << 10);

    f32x4 acc[4] = {zero, zero, zero, zero};
    float mrow[4], lsum[4];
#pragma unroll
    for (int q = 0; q < 4; ++q) { mrow[q] = -3.0e38f; lsum[q] = 0.f; }

    for (int t0 = 0; t0 < 1024; t0 += 64) {
        __syncthreads();
        { // stage K 64x64 and V^T 64x64 (2 rows/thread each)
            int r = tid >> 3, c8 = (tid & 7) * 8;
            *(ushort8v*)&Ks[r][c8]      = *(const ushort8v*)(kbase + (size_t)(t0 + r) * 512 + c8);
            *(ushort8v*)&Ks[r + 32][c8] = *(const ushort8v*)(kbase + (size_t)(t0 + r + 32) * 512 + c8);
            *(ushort8v*)&Vs[r][c8]      = *(const ushort8v*)(vbase + ((size_t)r << 10) + t0 + c8);
            *(ushort8v*)&Vs[r + 32][c8] = *(const ushort8v*)(vbase + ((size_t)(r + 32) << 10) + t0 + c8);
        }
        // BD loads (L3-resident, overlap staging)
        float bdv[4][4];
#pragma unroll
        for (int j = 0; j < 4; ++j) {
            int t = t0 + j * 16 + lrow;
#pragma unroll
            for (int q = 0; q < 4; ++q) {
                int u = urow + q;
                float v = bf2f(bdb[((size_t)u << 10) + t]);
                bdv[j][q] = (t == u + 1) ? 0.f : v;
            }
        }
        __syncthreads();
        uint32_t mw0[4], mw1[4];
#pragma unroll
        for (int q = 0; q < 4; ++q) {
            mw0[q] = Mw[urow + q - u0][t0 >> 5];
            mw1[q] = Mw[urow + q - u0][(t0 >> 5) + 1];
        }

        // scores: 4 t-groups of 16
        f32x4 s[4];
#pragma unroll
        for (int j = 0; j < 4; ++j) {
            bf16x8 k0 = *(const bf16x8*)&Ks[j * 16 + lrow][lkg * 8];
            bf16x8 k1 = *(const bf16x8*)&Ks[j * 16 + lrow][32 + lkg * 8];
            s[j] = mfma16(au1, k1, mfma16(au0, k0, zero));
        }
#pragma unroll
        for (int j = 0; j < 4; ++j) {
#pragma unroll
            for (int q = 0; q < 4; ++q) {
                float sv = fmaf(s[j][q], 0.125f, bdv[j][q]);
                uint32_t w = (j < 2) ? mw0[q] : mw1[q];
                if (!((w >> ((j & 1) * 16 + lrow)) & 1)) sv = -1.0e30f;
                s[j][q] = sv;
            }
        }
        // defer-max: local max, only reduce+rescale when it grows past THR
        float lmax[4];
#pragma unroll
        for (int q = 0; q < 4; ++q)
            lmax[q] = fmaxf(fmaxf(s[0][q], s[1][q]), fmaxf(s[2][q], s[3][q]));
        int need = (lmax[0] > mrow[0] + 8.f) | (lmax[1] > mrow[1] + 8.f) |
                   (lmax[2] > mrow[2] + 8.f) | (lmax[3] > mrow[3] + 8.f);
        if (__any(need)) {
            float rmx[4] = {lmax[0], lmax[1], lmax[2], lmax[3]};
#pragma unroll
            for (int off = 1; off < 16; off <<= 1)
#pragma unroll
                for (int q = 0; q < 4; ++q) rmx[q] = fmaxf(rmx[q], __shfl_xor(rmx[q], off));
#pragma unroll
            for (int q = 0; q < 4; ++q) {
                float mn = fmaxf(mrow[q], rmx[q]);
                float fr = __expf(mrow[q] - mn);
                mrow[q] = mn;
                lsum[q] *= fr;
#pragma unroll
                for (int jj = 0; jj < 4; ++jj) acc[jj][q] *= fr;
            }
        }
        // exp + per-lane partial sum + P store
#pragma unroll
        for (int j = 0; j < 4; ++j) {
#pragma unroll
            for (int q = 0; q < 4; ++q) {
                float p = __expf(s[j][q] - mrow[q]);
                lsum[q] += p;
                Ps[wave][lkg * 4 + q][j * 16 + lrow] = f2bf_native(p);
            }
        }
        // PV
        bf16x8 pa0 = *(const bf16x8*)&Ps[wave][lrow][lkg * 8];
        bf16x8 pa1 = *(const bf16x8*)&Ps[wave][lrow][32 + lkg * 8];
#pragma unroll
        for (int jj = 0; jj < 4; ++jj) {
            bf16x8 vb0 = *(const bf16x8*)&Vs[jj * 16 + lrow][lkg * 8];
            bf16x8 vb1 = *(const bf16x8*)&Vs[jj * 16 + lrow][32 + lkg * 8];
            acc[jj] = mfma16(pa1, vb1, mfma16(pa0, vb0, acc[jj]));
        }
    }

    // final cross-lane sum reduce (once), then write
#pragma unroll
    for (int off = 1; off < 16; off <<= 1)
#pragma unroll
        for (int q = 0; q < 4; ++q) lsum[q] += __shfl_xor(lsum[q], off);
#pragma unroll
    for (int q = 0; q < 4; ++q) {
        float inv = 1.0f / lsum[q];
        int u = urow + q;
#pragma unroll
        for (int jj = 0; jj < 4; ++jj) {
            int d = jj * 16 + lrow;
            xout[((size_t)(b * 1024 + u)) * 512 + h * 64 + d] = f2bf_native(acc[jj][q] * inv);
        }
    }
}

// ---------------------------------------------------------------------------
extern "C" void kernel_launch(void* const* d_in, const int* in_sizes, int n_in,
                              void* d_out, int out_size, void* d_ws, size_t ws_size,
                              hipStream_t stream) {
    const float* q    = (const float*)d_in[0];
    const float* k    = (const float*)d_in[1];
    const float* v    = (const float*)d_in[2];
    const float* pos  = (const float*)d_in[3];
    const int*   mask = (const int*)d_in[4];
    const float* Wq   = (const float*)d_in[5];
    const float* bq   = (const float*)d_in[6];
    const float* Wk   = (const float*)d_in[7];
    const float* bk   = (const float*)d_in[8];
    const float* Wv   = (const float*)d_in[9];
    const float* bv   = (const float*)d_in[10];
    const float* Wo   = (const float*)d_in[11];
    const float* bo   = (const float*)d_in[12];
    const float* Wp   = (const float*)d_in[13];
    const float* bias_u = (const float*)d_in[14];
    const float* bias_v = (const float*)d_in[15];
    float* out = (float*)d_out;

    unsigned short* ws = (unsigned short*)d_ws;
    constexpr size_t NQ  = (size_t)Bc * Tc * Dc;          // 4,194,304 elems
    constexpr size_t NP  = (size_t)Tc * Dc;               // 524,288
    constexpr size_t NMB = (size_t)Bc * Tc * 32;          // 262,144 words
    constexpr size_t NWB = (size_t)5 * 262144;            // 1,310,720 elems
    unsigned short* ws_qu = ws;
    unsigned short* ws_qv = ws_qu + NQ;
    unsigned short* ws_kh = ws_qv + NQ;
    unsigned short* ws_vT = ws_kh + NQ;
    unsigned short* ws_ph = ws_vT + NQ;
    uint32_t*       ws_mb = (uint32_t*)(ws_ph + NP);
    unsigned short* ws_wb = (unsigned short*)(ws_mb + NMB);
    unsigned short* ws_bd = ws_wb + NWB;

    constexpr size_t BD_FULL  = (size_t)64 * 1024 * 1024;   // elems
    constexpr size_t BD_SMALL = (size_t)8 * 1024 * 1024;
    const size_t base_bytes = (4 * NQ + NP + NWB) * 2 + NMB * 4;
    const bool full  = ws_size >= base_bytes + BD_FULL * 2;
    const bool tier2 = !full && ws_size >= base_bytes + (BD_SMALL + NQ) * 2;

    dim3 blk(256);
    pack_prep<<<33408, blk, 0, stream>>>(mask, ws_mb, Wq, Wk, Wv, Wp, Wo, ws_wb);
    proj4<<<dim3(4, 64, 4), blk, 0, stream>>>(q, k, v, pos, ws_wb, bq, bk, bv,
                                              bias_u, bias_v, ws_qu, ws_qv, ws_kh, ws_vT, ws_ph);

    if (full) {
        unsigned short* ws_x = ws_qv;  // qv dead after bd_gemm
        bd_gemm<<<dim3(8, 8, 64), blk, 0, stream>>>(ws_qv, ws_ph, ws_bd, 0);
        attn3<<<dim3(1024), blk, 0, stream>>>(ws_qu, ws_kh, ws_vT, ws_bd, ws_mb, ws_x, 0);
        gemm_out<<<dim3(4, 64), blk, 0, stream>>>(ws_x, ws_wb + 4 * 262144, bo, out);
    } else if (tier2) {
        unsigned short* ws_x = ws_bd + BD_SMALL;
        for (int b = 0; b < 8; ++b) {
            bd_gemm<<<dim3(8, 8, 8), blk, 0, stream>>>(ws_qv, ws_ph, ws_bd, b * 8);
            attn3<<<dim3(128), blk, 0, stream>>>(ws_qu, ws_kh, ws_vT, ws_bd, ws_mb, ws_x, b);
        }
        gemm_out<<<dim3(4, 64), blk, 0, stream>>>(ws_x, ws_wb + 4 * 262144, bo, out);
    }
}